// Round 9
// baseline (1768.774 us; speedup 1.0000x reference)
//
#include <hip/hip_runtime.h>
#include <hip/hip_bf16.h>

#define BB   8
#define TT   1024
#define NCBN 2
#define DD   128
#define KK   8192
#define MM   8192          // B*T queries per codebook

constexpr int OUT_IDX_OFF  = BB * 256 * TT;                // 2097152
constexpr int OUT_LOSS_OFF = OUT_IDX_OFF + BB * NCBN * TT; // 2113536

#define THR   0.45f        // >= 2*worst-case |y_bf16 - y_f32| (bound ~0.36)
#define QCAP  512
#define NSPL  4            // K-splits of 2048 codes

typedef __attribute__((ext_vector_type(8))) short   short8;   // 8 bf16
typedef __attribute__((ext_vector_type(4))) float   float4v;

__device__ __forceinline__ unsigned short f2bf(float v) {
    unsigned u = __float_as_uint(v);
    return (unsigned short)((u + 0x7FFFu + ((u >> 16) & 1u)) >> 16);  // RNE
}
__device__ __forceinline__ void gl_lds16(const void* g, void* l) {
    __builtin_amdgcn_global_load_lds(
        (const __attribute__((address_space(1))) unsigned int*)g,
        (__attribute__((address_space(3))) unsigned int*)l, 16, 0, 0);
}
__device__ __forceinline__ unsigned fmono(float v) {   // order-preserving u32
    unsigned u = __float_as_uint(v);
    return (u & 0x80000000u) ? ~u : (u | 0x80000000u);
}
__device__ __forceinline__ float fmono_inv(unsigned mu) {
    unsigned u = (mu & 0x80000000u) ? (mu & 0x7FFFFFFFu) : ~mu;
    return __uint_as_float(u);
}

// ---------------------------------------------------------------------------
// Prep (R6's proven version). Blocks 0..255: pack_x (transpose -> xbf bf16,
// x2, x32t, pmin/gminU init). Blocks 256..319: pack_c (bf16 + c2) + loss=0
// + gcnt=0. R1 ascending-d fmaf association throughout (bit-exact).
// ---------------------------------------------------------------------------
__global__ __launch_bounds__(256)
void prep_kernel(const float* __restrict__ x, const float* __restrict__ cb,
                 unsigned short* __restrict__ xbf, unsigned short* __restrict__ cbf,
                 float* __restrict__ x2, float* __restrict__ c2,
                 float* __restrict__ x32t, int contig,
                 unsigned long long* __restrict__ pmin,
                 unsigned int* __restrict__ gminU,
                 unsigned int* __restrict__ gcnt,
                 float* __restrict__ out) {
    const int bx = blockIdx.x;
    const int tid = threadIdx.x;

    if (bx >= 256) {   // ---- pack_c
        int g = (bx - 256) * 256 + tid;   // n*K + k
        if (g == 0) out[OUT_LOSS_OFF] = 0.f;
        if (bx == 256 && tid < 128) gcnt[tid] = 0u;
        const float4* crow = (const float4*)(cb + (size_t)g * DD);
        unsigned short* orow = cbf + (size_t)g * DD;
        float s = 0.f;
#pragma unroll 4
        for (int i2 = 0; i2 < 16; ++i2) {
            float4 v0 = crow[2 * i2];
            float4 v1 = crow[2 * i2 + 1];
            s = fmaf(v0.x, v0.x, s); s = fmaf(v0.y, v0.y, s);
            s = fmaf(v0.z, v0.z, s); s = fmaf(v0.w, v0.w, s);
            s = fmaf(v1.x, v1.x, s); s = fmaf(v1.y, v1.y, s);
            s = fmaf(v1.z, v1.z, s); s = fmaf(v1.w, v1.w, s);
            uint4 pk;
            pk.x = (unsigned)f2bf(v0.x) | ((unsigned)f2bf(v0.y) << 16);
            pk.y = (unsigned)f2bf(v0.z) | ((unsigned)f2bf(v0.w) << 16);
            pk.z = (unsigned)f2bf(v1.x) | ((unsigned)f2bf(v1.y) << 16);
            pk.w = (unsigned)f2bf(v1.z) | ((unsigned)f2bf(v1.w) << 16);
            *(uint4*)(orow + i2 * 8) = pk;
        }
        c2[g] = s;
        return;
    }

    // ---- pack_x: bx = ((b<<1)|n)*16 + t-tile (64-wide)
    __shared__ float Ld[DD][65];
    const int b = bx >> 5, n = (bx >> 4) & 1;
    const int t0 = (bx & 15) * 64;

    const float* base = x + ((size_t)(b * 256 + n * 128)) * TT + t0;
    const int dro = tid >> 2, q4 = tid & 3;
#pragma unroll
    for (int half = 0; half < 2; ++half) {
        int d = dro + half * 64;
        const float* rp = base + (size_t)d * TT + q4 * 16;
#pragma unroll
        for (int j = 0; j < 4; ++j) {
            float4 v = *(const float4*)(rp + j * 4);
            int t = q4 * 16 + j * 4;
            Ld[d][t + 0] = v.x; Ld[d][t + 1] = v.y;
            Ld[d][t + 2] = v.z; Ld[d][t + 3] = v.w;
        }
    }
    __syncthreads();

    if (tid < 64) {
        float s = 0.f;
        for (int d = 0; d < DD; ++d) { float v = Ld[d][tid]; s = fmaf(v, v, s); }
        size_t gi = (size_t)n * MM + b * TT + t0 + tid;
        x2[gi] = s;
        pmin[gi] = 0xFFFFFFFFFFFFFFFFull;
        gminU[gi] = fmono(3.4e38f);
    }

    unsigned short* orow0 = xbf + ((size_t)n * MM + b * TT + t0) * DD;
#pragma unroll
    for (int pp = 0; pp < 4; ++pp) {
        int u = tid + pp * 256;            // 1024 units = 64 rows x 16 segs
        int tt = u >> 4, sg = u & 15;
        unsigned short tmp[8];
#pragma unroll
        for (int j = 0; j < 8; ++j) tmp[j] = f2bf(Ld[sg * 8 + j][tt]);
        uint4 pk;
        pk.x = (unsigned)tmp[0] | ((unsigned)tmp[1] << 16);
        pk.y = (unsigned)tmp[2] | ((unsigned)tmp[3] << 16);
        pk.z = (unsigned)tmp[4] | ((unsigned)tmp[5] << 16);
        pk.w = (unsigned)tmp[6] | ((unsigned)tmp[7] << 16);
        *(uint4*)(orow0 + (size_t)tt * DD + sg * 8) = pk;
    }

    if (contig) {   // fp32 transposed copy for fast exact rescore/gather
        float* xrow0 = x32t + ((size_t)n * MM + b * TT + t0) * DD;
#pragma unroll
        for (int pp = 0; pp < 8; ++pp) {
            int u = tid + pp * 256;        // 2048 units = 64 rows x 32 f4-segs
            int tt = u >> 5, sg = u & 31;
            float4 v = { Ld[sg * 4 + 0][tt], Ld[sg * 4 + 1][tt],
                         Ld[sg * 4 + 2][tt], Ld[sg * 4 + 3][tt] };
            *(float4*)(xrow0 + (size_t)tt * DD + sg * 4) = v;
        }
    }
}

// ---------------------------------------------------------------------------
// Exact fp32 rescore: bit-identical association to the R1 passing kernel.
// atomicMin on (s_bits<<32 | k) = "min s, then lowest k" (s > 0 here).
// ---------------------------------------------------------------------------
__device__ void rescore_one(int n, int m, int k,
                            const float* __restrict__ xex, int contig,
                            const float* __restrict__ cb,
                            const float* __restrict__ x2, const float* __restrict__ c2,
                            unsigned long long* __restrict__ pmin) {
    const float* xp; int st;
    if (contig) { xp = xex + ((size_t)n * MM + m) * DD; st = 1; }
    else {
        int b = m >> 10, t = m & (TT - 1);
        xp = xex + ((size_t)(b * 256 + n * 128)) * TT + t; st = TT;
    }
    const float* cp = cb + ((size_t)(n * KK + k)) * DD;
    float xc = 0.f;
    for (int d = 0; d < DD; ++d)
        xc = fmaf(xp[(size_t)d * st], cp[d], xc);
    float u = x2[(size_t)n * MM + m] - 2.0f * xc;
    float s = u + c2[n * KK + k];
    unsigned long long pk = ((unsigned long long)__float_as_uint(s) << 32) | (unsigned)k;
    atomicMin(pmin + (size_t)n * MM + m, pk);
}

// ---------------------------------------------------------------------------
// Screen v9 = R5 skeleton, single MFMA pass w/ per-(thread,tq) top-2.
// grid 512: n=id&1, ks=(id>>1)&3, qt=id>>3 (combo=id&7 -> XCD-local slice).
// 256 thr, Qsh+Ash 32KB each, XOR-swizzled, gl_lds16 staging (R5 proven).
// Epilogue: top-2 (v1,c1,v2) per (thread,tq), rare m16-gated insert.
// End: slice-min reduce -> publish/fetch gminU -> thr=gmin+THR; enqueue c1
// (v1<=thr) / own-code rescan subtasks (v2<=thr); exact fp32 drain; fused
// gather via arrival counter (R7 machinery).
// ---------------------------------------------------------------------------
__global__ __launch_bounds__(256, 2)
void screen_kernel(const unsigned short* __restrict__ xbf,
                   const unsigned short* __restrict__ cbf,
                   const float* __restrict__ c2,
                   const float* __restrict__ xex, int contig,
                   const float* __restrict__ cb32,
                   const float* __restrict__ x2,
                   unsigned int* __restrict__ gminU,
                   unsigned long long* __restrict__ pmin,
                   unsigned int* __restrict__ gcnt,
                   float* __restrict__ out) {
    __shared__ __align__(16) unsigned short Qsh[128 * 128];   // 32 KB
    __shared__ __align__(16) unsigned short Ash[128 * 128];   // 32 KB
    __shared__ float        c2s[128];
    __shared__ unsigned int minU[128];
    __shared__ float        gthr[128];
    __shared__ unsigned int qcnt;
    __shared__ unsigned int queue[QCAP];                      // 2 KB
    __shared__ int          kid[128];
    __shared__ float        wred[4];
    __shared__ int          dflag;

    const int tid = threadIdx.x;
    const int id  = blockIdx.x;
    const int n   = id & 1;
    const int ks  = (id >> 1) & 3;
    const int qt  = id >> 3;           // 0..63
    const int m0  = qt * 128;
    const int k0  = ks * 2048;
    const size_t gq = (size_t)n * MM + m0;

    const int wave = tid >> 6, lane = tid & 63;
    const int cw = wave & 1, qw = wave >> 1;
    const int quad = lane >> 4, l15 = lane & 15;

    // per-lane staging offsets (bytes within one 32 KB tile), 8 issues/wave
    int goff[8];
#pragma unroll
    for (int p = 0; p < 8; ++p) {
        int u   = (p * 4 + wave) * 64 + lane;
        int row = u >> 4;
        int seg = (u & 15) ^ (row & 15);
        goff[p] = (row * DD + seg * 8) * 2;
    }

    // ---- stage queries into Qsh (async)
    {
        const char* src = (const char*)(xbf + ((size_t)n * MM + m0) * DD);
#pragma unroll
        for (int p = 0; p < 8; ++p)
            gl_lds16(src + goff[p], &Qsh[(p * 4 + wave) * 512]);
    }
    if (tid < 128) minU[tid] = 0xFFFFFFFFu;
    if (tid == 0)  qcnt = 0;
    __syncthreads();

    // ---- query B-fragments (whole D=128) register-resident: 64 VGPRs
    short8 bfr[4][4];                      // [tq][k4]
#pragma unroll
    for (int tq = 0; tq < 4; ++tq) {
        int q = qw * 64 + tq * 16 + l15;   // q&15 == l15
#pragma unroll
        for (int k4 = 0; k4 < 4; ++k4) {
            int seg = k4 * 4 + quad;
            bfr[tq][k4] = *(const short8*)(&Qsh[q * 128 + ((seg ^ l15) * 8)]);
        }
    }

    float    v1[4] = {3.4e38f, 3.4e38f, 3.4e38f, 3.4e38f};
    float    v2[4] = {3.4e38f, 3.4e38f, 3.4e38f, 3.4e38f};
    unsigned c1[4] = {0, 0, 0, 0};

    const char*  asrc0 = (const char*)(cbf + ((size_t)n * KK + k0) * DD);
    const float* c2p   = c2 + (size_t)n * KK + k0;

    for (int ch = 0; ch < 16; ++ch) {
        __syncthreads();               // Ash free
        {   // async stage code chunk -> Ash
            const char* src = asrc0 + (size_t)ch * (128 * DD * 2);
#pragma unroll
            for (int p = 0; p < 8; ++p)
                gl_lds16(src + goff[p], &Ash[(p * 4 + wave) * 512]);
            if (tid < 32)
                *(float4*)&c2s[tid * 4] =
                    *(const float4*)(c2p + ch * 128 + tid * 4);
        }
        __syncthreads();               // Ash ready (vmcnt drained)

        float4v acc[4][4];             // [tc][tq]: 64 VGPRs
#pragma unroll
        for (int tc = 0; tc < 4; ++tc)
#pragma unroll
            for (int tq = 0; tq < 4; ++tq)
                acc[tc][tq] = (float4v){0.f, 0.f, 0.f, 0.f};

#pragma unroll
        for (int k4 = 0; k4 < 4; ++k4) {
            short8 a[4];
#pragma unroll
            for (int tc = 0; tc < 4; ++tc) {
                int r = cw * 64 + tc * 16 + l15;       // r&15 == l15
                int seg = k4 * 4 + quad;
                a[tc] = *(const short8*)(&Ash[r * 128 + ((seg ^ l15) * 8)]);
            }
#pragma unroll
            for (int tc = 0; tc < 4; ++tc)
#pragma unroll
                for (int tq = 0; tq < 4; ++tq)
                    acc[tc][tq] = __builtin_amdgcn_mfma_f32_16x16x32_bf16(
                        a[tc], bfr[tq][k4], acc[tc][tq], 0, 0, 0);
        }

        // epilogue: y = c2 - 2*xc; top-2 update, rare gated insert path
#pragma unroll
        for (int tq = 0; tq < 4; ++tq) {
            float m16 = 3.4e38f;
#pragma unroll
            for (int tc = 0; tc < 4; ++tc) {
                float4v c2r = *(const float4v*)(&c2s[cw * 64 + tc * 16 + quad * 4]);
#pragma unroll
                for (int rg = 0; rg < 4; ++rg)
                    m16 = fminf(m16, fmaf(-2.0f, acc[tc][tq][rg], c2r[rg]));
            }
            if (m16 < v2[tq]) {
#pragma unroll
                for (int tc = 0; tc < 4; ++tc) {
                    float4v c2r = *(const float4v*)(&c2s[cw * 64 + tc * 16 + quad * 4]);
#pragma unroll
                    for (int rg = 0; rg < 4; ++rg) {
                        float y = fmaf(-2.0f, acc[tc][tq][rg], c2r[rg]);
                        if (y < v2[tq]) {
                            unsigned code = (unsigned)(ch * 128 + cw * 64 + tc * 16 + quad * 4 + rg);
                            if (y < v1[tq]) { v2[tq] = v1[tq]; v1[tq] = y; c1[tq] = code; }
                            else             v2[tq] = y;
                        }
                    }
                }
            }
        }
    }

    // ---- slice-min reduce per query; publish + fetch global min
#pragma unroll
    for (int tq = 0; tq < 4; ++tq) {
        float v = v1[tq];
        v = fminf(v, __shfl_xor(v, 16, 64));
        v = fminf(v, __shfl_xor(v, 32, 64));
        if (quad == 0)
            atomicMin(&minU[qw * 64 + tq * 16 + l15], fmono(v));
    }
    __syncthreads();
    if (tid < 128) {
        unsigned mine = minU[tid];
        unsigned old  = atomicMin(&gminU[gq + tid], mine);
        gthr[tid] = fmono_inv(old < mine ? old : mine) + THR;
    }
    __syncthreads();

    // ---- enqueue candidates: entry = (q<<12) | (type<<11) | payload
#pragma unroll
    for (int tq = 0; tq < 4; ++tq) {
        unsigned q = (unsigned)(qw * 64 + tq * 16 + l15);
        float g = gthr[q];
        if (v1[tq] <= g) {
            unsigned idx = atomicAdd(&qcnt, 1u);
            unsigned e = (q << 12) | c1[tq];
            if (idx < QCAP) queue[idx] = e;
            else rescore_one(n, m0 + (int)q, k0 + (int)c1[tq],
                             xex, contig, cb32, x2, c2, pmin);
        }
        if (v2[tq] <= g) {             // depth>=2 possible: rescan own codes
#pragma unroll
            for (int chq = 0; chq < 8; ++chq) {
                unsigned idx = atomicAdd(&qcnt, 1u);
                unsigned e = (q << 12) | (1u << 11)
                           | ((unsigned)cw << 5) | ((unsigned)quad << 3) | (unsigned)chq;
                if (idx < QCAP) queue[idx] = e;
                else {
                    for (int c2h = 0; c2h < 2; ++c2h)
                        for (int tc = 0; tc < 4; ++tc)
                            for (int rg = 0; rg < 4; ++rg)
                                rescore_one(n, m0 + (int)q,
                                            k0 + (chq * 2 + c2h) * 128 + cw * 64 + tc * 16 + quad * 4 + rg,
                                            xex, contig, cb32, x2, c2, pmin);
                }
            }
        }
    }
    __syncthreads();

    // ---- drain: exact fp32 rescore
    unsigned total = qcnt; if (total > QCAP) total = QCAP;
    for (unsigned i = tid; i < total; i += 256) {
        unsigned e = queue[i];
        unsigned q = e >> 12;
        if (e & (1u << 11)) {
            int cw2 = (int)((e >> 5) & 1u), qd = (int)((e >> 3) & 3u), chq = (int)(e & 7u);
            for (int c2h = 0; c2h < 2; ++c2h)
                for (int tc = 0; tc < 4; ++tc)
                    for (int rg = 0; rg < 4; ++rg)
                        rescore_one(n, m0 + (int)q,
                                    k0 + (chq * 2 + c2h) * 128 + cw2 * 64 + tc * 16 + qd * 4 + rg,
                                    xex, contig, cb32, x2, c2, pmin);
        } else {
            rescore_one(n, m0 + (int)q, k0 + (int)(e & 2047u),
                        xex, contig, cb32, x2, c2, pmin);
        }
    }

    // ---- arrival: last split-block for (n,qt) gathers inline
    __threadfence();
    __syncthreads();
    if (tid == 0)
        dflag = (atomicAdd(&gcnt[(n << 6) | qt], 1u) == NSPL - 1) ? 1 : 0;
    __syncthreads();
    if (!dflag) return;
    __threadfence();

    const int b = qt >> 3;
    const int t0g = (qt & 7) * 128;
    if (tid < 128) {
        unsigned long long e = atomicMin(&pmin[gq + tid], 0xFFFFFFFFFFFFFFFFull);
        int k = (int)(e & 0xFFFFFFFFull);
        kid[tid] = k;
        out[OUT_IDX_OFF + (b * NCBN + n) * TT + t0g + tid] = (float)k;
    }
    __syncthreads();

    const int q = tid & 127, hf = tid >> 7;
    const int k = kid[q];
    const float* cp = cb32 + ((size_t)n * KK + k) * DD + hf * 64;
    const float* xp; int st;
    if (contig) { xp = xex + ((size_t)n * MM + m0 + q) * DD + hf * 64; st = 1; }
    else        { xp = xex + ((size_t)(b * 256 + n * 128 + hf * 64)) * TT + t0g + q; st = TT; }
    float* ob = out + ((size_t)(b * 256 + n * 128 + hf * 64)) * TT + t0g + q;

    float lsum = 0.f;
#pragma unroll 4
    for (int j = 0; j < 64; ++j) {
        float qv = cp[j];
        float xv = xp[(size_t)j * st];
        ob[(size_t)j * TT] = qv;
        float e = xv - qv; lsum = fmaf(e, e, lsum);
    }

#pragma unroll
    for (int o = 32; o > 0; o >>= 1) lsum += __shfl_down(lsum, o, 64);
    if (lane == 0) wred[wave] = lsum;
    __syncthreads();
    if (tid == 0) {
        float tot = wred[0] + wred[1] + wred[2] + wred[3];
        atomicAdd(out + OUT_LOSS_OFF, tot * 2.384185791015625e-7f);  // 2^-22
    }
}

// ---------------------------------------------------------------------------
extern "C" void kernel_launch(void* const* d_in, const int* in_sizes, int n_in,
                              void* d_out, int out_size, void* d_ws, size_t ws_size,
                              hipStream_t stream) {
    (void)in_sizes; (void)n_in; (void)out_size;
    const float* x  = (const float*)d_in[0];
    const float* cb = (const float*)d_in[1];
    float* out = (float*)d_out;

    char* ws = (char*)d_ws;
    unsigned short* xbf = (unsigned short*)(ws);                       // 4 MiB
    unsigned short* cbf = (unsigned short*)(ws + (4u << 20));          // 4 MiB
    float* x2 = (float*)(ws + (8u << 20));                             // 64 KiB
    float* c2 = (float*)(ws + (8u << 20) + (64u << 10));               // 64 KiB
    unsigned long long* pmin =
        (unsigned long long*)(ws + (8u << 20) + (128u << 10));         // 128 KiB
    unsigned int* gminU =
        (unsigned int*)(ws + (8u << 20) + (256u << 10));               // 64 KiB
    unsigned int* gcnt =
        (unsigned int*)(ws + (8u << 20) + (320u << 10));               // 512 B
    float* x32t = (float*)(ws + (9u << 20));                           // 8 MiB

    const size_t need = (9u << 20) + (size_t)NCBN * MM * DD * 4;
    const int contig = (ws_size >= need) ? 1 : 0;
    const float* xex = contig ? x32t : x;

    prep_kernel<<<dim3(320), 256, 0, stream>>>(x, cb, xbf, cbf, x2, c2,
                                               x32t, contig, pmin, gminU, gcnt, out);
    screen_kernel<<<dim3(512), 256, 0, stream>>>(xbf, cbf, c2, xex, contig,
                                                 cb, x2, gminU, pmin, gcnt, out);
}

// Round 10
// 274.416 us; speedup vs baseline: 6.4456x; 6.4456x over previous
//
#include <hip/hip_runtime.h>
#include <hip/hip_bf16.h>

#define BB   8
#define TT   1024
#define NCBN 2
#define DD   128
#define KK   8192
#define MM   8192          // B*T queries per codebook

constexpr int OUT_IDX_OFF  = BB * 256 * TT;                // 2097152
constexpr int OUT_LOSS_OFF = OUT_IDX_OFF + BB * NCBN * TT; // 2113536

#define THR   0.45f        // >= 2*worst-case |y_bf16 - y_f32| (bound ~0.36)
#define QCAP  768
#define NSPL  4            // K-splits of 2048 codes

typedef __attribute__((ext_vector_type(8))) short   short8;   // 8 bf16
typedef __attribute__((ext_vector_type(4))) float   float4v;

__device__ __forceinline__ unsigned short f2bf(float v) {
    unsigned u = __float_as_uint(v);
    return (unsigned short)((u + 0x7FFFu + ((u >> 16) & 1u)) >> 16);  // RNE
}
__device__ __forceinline__ void gl_lds16(const void* g, void* l) {
    __builtin_amdgcn_global_load_lds(
        (const __attribute__((address_space(1))) unsigned int*)g,
        (__attribute__((address_space(3))) unsigned int*)l, 16, 0, 0);
}
__device__ __forceinline__ unsigned fmono(float v) {   // order-preserving u32
    unsigned u = __float_as_uint(v);
    return (u & 0x80000000u) ? ~u : (u | 0x80000000u);
}
__device__ __forceinline__ float fmono_inv(unsigned mu) {
    unsigned u = (mu & 0x80000000u) ? (mu & 0x7FFFFFFFu) : ~mu;
    return __uint_as_float(u);
}

// ---------------------------------------------------------------------------
// Prep (proven R6-R9). Blocks 0..255: pack_x (transpose -> xbf bf16, x2,
// x32t, pmin init). Blocks 256..319: pack_c (bf16 + c2) + loss=0 + gcnt=0.
// R1 ascending-d fmaf association throughout (bit-exact with passing ref).
// ---------------------------------------------------------------------------
__global__ __launch_bounds__(256)
void prep_kernel(const float* __restrict__ x, const float* __restrict__ cb,
                 unsigned short* __restrict__ xbf, unsigned short* __restrict__ cbf,
                 float* __restrict__ x2, float* __restrict__ c2,
                 float* __restrict__ x32t, int contig,
                 unsigned long long* __restrict__ pmin,
                 unsigned int* __restrict__ gcnt,
                 float* __restrict__ out) {
    const int bx = blockIdx.x;
    const int tid = threadIdx.x;

    if (bx >= 256) {   // ---- pack_c
        int g = (bx - 256) * 256 + tid;   // n*K + k
        if (g == 0) out[OUT_LOSS_OFF] = 0.f;
        if (bx == 256 && tid < 128) gcnt[tid] = 0u;
        const float4* crow = (const float4*)(cb + (size_t)g * DD);
        unsigned short* orow = cbf + (size_t)g * DD;
        float s = 0.f;
#pragma unroll 4
        for (int i2 = 0; i2 < 16; ++i2) {
            float4 v0 = crow[2 * i2];
            float4 v1 = crow[2 * i2 + 1];
            s = fmaf(v0.x, v0.x, s); s = fmaf(v0.y, v0.y, s);
            s = fmaf(v0.z, v0.z, s); s = fmaf(v0.w, v0.w, s);
            s = fmaf(v1.x, v1.x, s); s = fmaf(v1.y, v1.y, s);
            s = fmaf(v1.z, v1.z, s); s = fmaf(v1.w, v1.w, s);
            uint4 pk;
            pk.x = (unsigned)f2bf(v0.x) | ((unsigned)f2bf(v0.y) << 16);
            pk.y = (unsigned)f2bf(v0.z) | ((unsigned)f2bf(v0.w) << 16);
            pk.z = (unsigned)f2bf(v1.x) | ((unsigned)f2bf(v1.y) << 16);
            pk.w = (unsigned)f2bf(v1.z) | ((unsigned)f2bf(v1.w) << 16);
            *(uint4*)(orow + i2 * 8) = pk;
        }
        c2[g] = s;
        return;
    }

    // ---- pack_x: bx = ((b<<1)|n)*16 + t-tile (64-wide)
    __shared__ float Ld[DD][65];
    const int b = bx >> 5, n = (bx >> 4) & 1;
    const int t0 = (bx & 15) * 64;

    const float* base = x + ((size_t)(b * 256 + n * 128)) * TT + t0;
    const int dro = tid >> 2, q4 = tid & 3;
#pragma unroll
    for (int half = 0; half < 2; ++half) {
        int d = dro + half * 64;
        const float* rp = base + (size_t)d * TT + q4 * 16;
#pragma unroll
        for (int j = 0; j < 4; ++j) {
            float4 v = *(const float4*)(rp + j * 4);
            int t = q4 * 16 + j * 4;
            Ld[d][t + 0] = v.x; Ld[d][t + 1] = v.y;
            Ld[d][t + 2] = v.z; Ld[d][t + 3] = v.w;
        }
    }
    __syncthreads();

    if (tid < 64) {
        float s = 0.f;
        for (int d = 0; d < DD; ++d) { float v = Ld[d][tid]; s = fmaf(v, v, s); }
        size_t gi = (size_t)n * MM + b * TT + t0 + tid;
        x2[gi] = s;
        pmin[gi] = 0xFFFFFFFFFFFFFFFFull;
    }

    unsigned short* orow0 = xbf + ((size_t)n * MM + b * TT + t0) * DD;
#pragma unroll
    for (int pp = 0; pp < 4; ++pp) {
        int u = tid + pp * 256;            // 1024 units = 64 rows x 16 segs
        int tt = u >> 4, sg = u & 15;
        unsigned short tmp[8];
#pragma unroll
        for (int j = 0; j < 8; ++j) tmp[j] = f2bf(Ld[sg * 8 + j][tt]);
        uint4 pk;
        pk.x = (unsigned)tmp[0] | ((unsigned)tmp[1] << 16);
        pk.y = (unsigned)tmp[2] | ((unsigned)tmp[3] << 16);
        pk.z = (unsigned)tmp[4] | ((unsigned)tmp[5] << 16);
        pk.w = (unsigned)tmp[6] | ((unsigned)tmp[7] << 16);
        *(uint4*)(orow0 + (size_t)tt * DD + sg * 8) = pk;
    }

    if (contig) {   // fp32 transposed copy for fast exact rescore/gather
        float* xrow0 = x32t + ((size_t)n * MM + b * TT + t0) * DD;
#pragma unroll
        for (int pp = 0; pp < 8; ++pp) {
            int u = tid + pp * 256;        // 2048 units = 64 rows x 32 f4-segs
            int tt = u >> 5, sg = u & 31;
            float4 v = { Ld[sg * 4 + 0][tt], Ld[sg * 4 + 1][tt],
                         Ld[sg * 4 + 2][tt], Ld[sg * 4 + 3][tt] };
            *(float4*)(xrow0 + (size_t)tt * DD + sg * 4) = v;
        }
    }
}

// ---------------------------------------------------------------------------
// Exact fp32 rescore: bit-identical association to the R1 passing kernel.
// atomicMin on (s_bits<<32 | k) = "min s, then lowest k" (s > 0 here).
// ---------------------------------------------------------------------------
__device__ void rescore_one(int n, int m, int k,
                            const float* __restrict__ xex, int contig,
                            const float* __restrict__ cb,
                            const float* __restrict__ x2, const float* __restrict__ c2,
                            unsigned long long* __restrict__ pmin) {
    const float* xp; int st;
    if (contig) { xp = xex + ((size_t)n * MM + m) * DD; st = 1; }
    else {
        int b = m >> 10, t = m & (TT - 1);
        xp = xex + ((size_t)(b * 256 + n * 128)) * TT + t; st = TT;
    }
    const float* cp = cb + ((size_t)(n * KK + k)) * DD;
    float xc = 0.f;
    for (int d = 0; d < DD; ++d)
        xc = fmaf(xp[(size_t)d * st], cp[d], xc);
    float u = x2[(size_t)n * MM + m] - 2.0f * xc;
    float s = u + c2[n * KK + k];
    unsigned long long pk = ((unsigned long long)__float_as_uint(s) << 32) | (unsigned)k;
    atomicMin(pmin + (size_t)n * MM + m, pk);
}

// ---------------------------------------------------------------------------
// Screen v10 = R5's proven two-phase kernel verbatim + fused gather tail.
// grid 512 x 256 thr: n=id&1, ks=(id>>1)&3, qt=id>>3 (combo=id&7 -> each XCD
// keeps one 1-MB code stream L2-resident). Qsh+Ash 32 KB XOR-swizzled,
// gl_lds16 async staging. Phase 0: exact bf16 slice-min per query; phase 1:
// identical rescan collecting y <= min+THR (candidate set provably contains
// the fp32 argmin); drain = exact fp32 rescore. Last split-block per (n,qt)
// gathers quantized rows + indices + loss (R7/R9-proven arrival machinery).
// ---------------------------------------------------------------------------
__global__ __launch_bounds__(256, 2)
void screen_kernel(const unsigned short* __restrict__ xbf,
                   const unsigned short* __restrict__ cbf,
                   const float* __restrict__ c2,
                   const float* __restrict__ xex, int contig,
                   const float* __restrict__ cb32,
                   const float* __restrict__ x2,
                   unsigned long long* __restrict__ pmin,
                   unsigned int* __restrict__ gcnt,
                   float* __restrict__ out) {
    __shared__ __align__(16) unsigned short Qsh[128 * 128];   // 32 KB
    __shared__ __align__(16) unsigned short Ash[128 * 128];   // 32 KB
    __shared__ unsigned int minU[128];
    __shared__ float        c2s[128];
    __shared__ unsigned int qcnt;
    __shared__ unsigned int queue[QCAP];                      // 3 KB
    __shared__ int          kid[128];
    __shared__ float        wred[4];
    __shared__ int          dflag;

    const int tid = threadIdx.x;
    const int id  = blockIdx.x;
    const int n   = id & 1;
    const int ks  = (id >> 1) & 3;
    const int qt  = id >> 3;           // 0..63
    const int m0  = qt * 128;
    const int k0  = ks * 2048;
    const size_t gq = (size_t)n * MM + m0;

    const int wave = tid >> 6, lane = tid & 63;
    const int cw = wave & 1, qw = wave >> 1;
    const int quad = lane >> 4, l15 = lane & 15;

    // per-lane staging offsets (bytes within one 32 KB tile), 8 issues/wave
    int goff[8];
#pragma unroll
    for (int p = 0; p < 8; ++p) {
        int u   = (p * 4 + wave) * 64 + lane;
        int row = u >> 4;
        int seg = (u & 15) ^ (row & 15);
        goff[p] = (row * DD + seg * 8) * 2;
    }

    // ---- stage queries into Qsh (async)
    {
        const char* src = (const char*)(xbf + ((size_t)n * MM + m0) * DD);
#pragma unroll
        for (int p = 0; p < 8; ++p)
            gl_lds16(src + goff[p], &Qsh[(p * 4 + wave) * 512]);
    }
    if (tid < 128) minU[tid] = 0xFFFFFFFFu;
    if (tid == 0)  qcnt = 0;
    __syncthreads();

    // ---- query B-fragments (whole D=128) register-resident: 64 VGPRs
    short8 bfr[4][4];                      // [tq][k4]
#pragma unroll
    for (int tq = 0; tq < 4; ++tq) {
        int q = qw * 64 + tq * 16 + l15;   // q&15 == l15
#pragma unroll
        for (int k4 = 0; k4 < 4; ++k4) {
            int seg = k4 * 4 + quad;
            bfr[tq][k4] = *(const short8*)(&Qsh[q * 128 + ((seg ^ l15) * 8)]);
        }
    }

    float mloc[4] = {3.4e38f, 3.4e38f, 3.4e38f, 3.4e38f};
    float thr[4]  = {3.4e38f, 3.4e38f, 3.4e38f, 3.4e38f};

    const char*  asrc0 = (const char*)(cbf + ((size_t)n * KK + k0) * DD);
    const float* c2p   = c2 + (size_t)n * KK + k0;

#pragma unroll
    for (int phase = 0; phase < 2; ++phase) {
        for (int ch = 0; ch < 16; ++ch) {
            __syncthreads();               // Ash free
            {   // async stage code chunk -> Ash
                const char* src = asrc0 + (size_t)ch * (128 * DD * 2);
#pragma unroll
                for (int p = 0; p < 8; ++p)
                    gl_lds16(src + goff[p], &Ash[(p * 4 + wave) * 512]);
                if (tid < 32)
                    *(float4*)&c2s[tid * 4] =
                        *(const float4*)(c2p + ch * 128 + tid * 4);
            }
            __syncthreads();               // Ash ready (vmcnt drained)

            float4v acc[4][4];             // [tc][tq]: 64 AGPRs
#pragma unroll
            for (int tc = 0; tc < 4; ++tc)
#pragma unroll
                for (int tq = 0; tq < 4; ++tq)
                    acc[tc][tq] = (float4v){0.f, 0.f, 0.f, 0.f};

#pragma unroll
            for (int k4 = 0; k4 < 4; ++k4) {
                short8 a[4];
#pragma unroll
                for (int tc = 0; tc < 4; ++tc) {
                    int r = cw * 64 + tc * 16 + l15;       // r&15 == l15
                    int seg = k4 * 4 + quad;
                    a[tc] = *(const short8*)(&Ash[r * 128 + ((seg ^ l15) * 8)]);
                }
#pragma unroll
                for (int tc = 0; tc < 4; ++tc)
#pragma unroll
                    for (int tq = 0; tq < 4; ++tq)
                        acc[tc][tq] = __builtin_amdgcn_mfma_f32_16x16x32_bf16(
                            a[tc], bfr[tq][k4], acc[tc][tq], 0, 0, 0);
            }

            // epilogue: y = c2 - 2*xc  (x2 query-constant, argmin-invariant)
#pragma unroll
            for (int tc = 0; tc < 4; ++tc) {
                float4v c2r = *(const float4v*)(&c2s[cw * 64 + tc * 16 + quad * 4]);
#pragma unroll
                for (int tq = 0; tq < 4; ++tq) {
                    float y0 = fmaf(-2.0f, acc[tc][tq][0], c2r[0]);
                    float y1 = fmaf(-2.0f, acc[tc][tq][1], c2r[1]);
                    float y2 = fmaf(-2.0f, acc[tc][tq][2], c2r[2]);
                    float y3 = fmaf(-2.0f, acc[tc][tq][3], c2r[3]);
                    float m4 = fminf(fminf(y0, y1), fminf(y2, y3));
                    if (phase == 0) {
                        mloc[tq] = fminf(mloc[tq], m4);
                    } else if (m4 <= thr[tq]) {
                        float yv[4] = {y0, y1, y2, y3};
#pragma unroll
                        for (int rg = 0; rg < 4; ++rg) {
                            if (yv[rg] <= thr[tq]) {
                                unsigned idx  = atomicAdd(&qcnt, 1u);
                                unsigned code = (unsigned)(ch * 128 + cw * 64 + tc * 16 + quad * 4 + rg);
                                unsigned q    = (unsigned)(qw * 64 + tq * 16 + l15);
                                if (idx < QCAP) queue[idx] = (q << 11) | code;
                                else rescore_one(n, m0 + (int)q, k0 + (int)code,
                                                 xex, contig, cb32, x2, c2, pmin);
                            }
                        }
                    }
                }
            }
        }

        if (phase == 0) {
            // merge per-query mins: shuffle across quads, then LDS atomicMin
#pragma unroll
            for (int tq = 0; tq < 4; ++tq) {
                float v = mloc[tq];
                v = fminf(v, __shfl_xor(v, 16, 64));
                v = fminf(v, __shfl_xor(v, 32, 64));
                if (quad == 0)
                    atomicMin(&minU[qw * 64 + tq * 16 + l15], fmono(v));
            }
            __syncthreads();
#pragma unroll
            for (int tq = 0; tq < 4; ++tq)
                thr[tq] = fmono_inv(minU[qw * 64 + tq * 16 + l15]) + THR;
        }
    }

    __syncthreads();
    // ---- drain: exact fp32 rescore of collected candidates
    unsigned total = qcnt; if (total > QCAP) total = QCAP;
    for (unsigned i = tid; i < total; i += 256) {
        unsigned e = queue[i];
        rescore_one(n, m0 + (int)(e >> 11), k0 + (int)(e & 2047u),
                    xex, contig, cb32, x2, c2, pmin);
    }

    // ---- arrival: last split-block for (n,qt) gathers inline
    __threadfence();
    __syncthreads();
    if (tid == 0)
        dflag = (atomicAdd(&gcnt[(n << 6) | qt], 1u) == NSPL - 1) ? 1 : 0;
    __syncthreads();
    if (!dflag) return;
    __threadfence();

    const int b = qt >> 3;
    const int t0g = (qt & 7) * 128;
    if (tid < 128) {
        unsigned long long e = atomicMin(&pmin[gq + tid], 0xFFFFFFFFFFFFFFFFull);
        int k = (int)(e & 0xFFFFFFFFull);
        kid[tid] = k;
        out[OUT_IDX_OFF + (b * NCBN + n) * TT + t0g + tid] = (float)k;
    }
    __syncthreads();

    const int q = tid & 127, hf = tid >> 7;
    const int k = kid[q];
    const float* cp = cb32 + ((size_t)n * KK + k) * DD + hf * 64;
    const float* xp; int st;
    if (contig) { xp = xex + ((size_t)n * MM + m0 + q) * DD + hf * 64; st = 1; }
    else        { xp = xex + ((size_t)(b * 256 + n * 128 + hf * 64)) * TT + t0g + q; st = TT; }
    float* ob = out + ((size_t)(b * 256 + n * 128 + hf * 64)) * TT + t0g + q;

    float lsum = 0.f;
#pragma unroll 4
    for (int j = 0; j < 64; ++j) {
        float qv = cp[j];
        float xv = xp[(size_t)j * st];
        ob[(size_t)j * TT] = qv;
        float e = xv - qv; lsum = fmaf(e, e, lsum);
    }

#pragma unroll
    for (int o = 32; o > 0; o >>= 1) lsum += __shfl_down(lsum, o, 64);
    if (lane == 0) wred[wave] = lsum;
    __syncthreads();
    if (tid == 0) {
        float tot = wred[0] + wred[1] + wred[2] + wred[3];
        atomicAdd(out + OUT_LOSS_OFF, tot * 2.384185791015625e-7f);  // 2^-22
    }
}

// ---------------------------------------------------------------------------
extern "C" void kernel_launch(void* const* d_in, const int* in_sizes, int n_in,
                              void* d_out, int out_size, void* d_ws, size_t ws_size,
                              hipStream_t stream) {
    (void)in_sizes; (void)n_in; (void)out_size;
    const float* x  = (const float*)d_in[0];
    const float* cb = (const float*)d_in[1];
    float* out = (float*)d_out;

    char* ws = (char*)d_ws;
    unsigned short* xbf = (unsigned short*)(ws);                       // 4 MiB
    unsigned short* cbf = (unsigned short*)(ws + (4u << 20));          // 4 MiB
    float* x2 = (float*)(ws + (8u << 20));                             // 64 KiB
    float* c2 = (float*)(ws + (8u << 20) + (64u << 10));               // 64 KiB
    unsigned long long* pmin =
        (unsigned long long*)(ws + (8u << 20) + (128u << 10));         // 128 KiB
    unsigned int* gcnt =
        (unsigned int*)(ws + (8u << 20) + (256u << 10));               // 512 B
    float* x32t = (float*)(ws + (9u << 20));                           // 8 MiB

    const size_t need = (9u << 20) + (size_t)NCBN * MM * DD * 4;
    const int contig = (ws_size >= need) ? 1 : 0;
    const float* xex = contig ? x32t : x;

    prep_kernel<<<dim3(320), 256, 0, stream>>>(x, cb, xbf, cbf, x2, c2,
                                               x32t, contig, pmin, gcnt, out);
    screen_kernel<<<dim3(512), 256, 0, stream>>>(xbf, cbf, c2, xex, contig,
                                                 cb, x2, pmin, gcnt, out);
}